// Round 6
// baseline (603.240 us; speedup 1.0000x reference)
//
#include <hip/hip_runtime.h>
#include <math.h>

#define NP 131072

typedef unsigned short u16;
typedef __bf16 v8bf __attribute__((ext_vector_type(8)));
typedef unsigned short v8u __attribute__((ext_vector_type(8)));
typedef float v4f __attribute__((ext_vector_type(4)));

#define MFMA(a, b, c) __builtin_amdgcn_mfma_f32_16x16x32_bf16(a, b, c, 0, 0, 0)
#define EPS 1.1920928955078125e-07f

__device__ __forceinline__ u16 f2b(float f) { return __builtin_bit_cast(u16, (__bf16)f); }
__device__ __forceinline__ unsigned f2b2(float a, float b) {
    return (unsigned)f2b(a) | ((unsigned)f2b(b) << 16);
}
__device__ __forceinline__ float frcp(float x) { return __builtin_amdgcn_rcpf(x); }
__device__ __forceinline__ float frsq(float x) { return __builtin_amdgcn_rsqf(x); }
__device__ __forceinline__ v8bf ldfrag(const u16* p) { return *(const v8bf*)p; }
__device__ __forceinline__ v8bf zfrag() { v8u z = {0,0,0,0,0,0,0,0}; return __builtin_bit_cast(v8bf, z); }

// ---- weight prep: transpose + bf16 into ws ----
// layout (u16): qkvT[192][64] @0 ; woT[64][64] @12288 ; w1T[128][64] @16384 ;
//               w2T[64][128] @24576 ; projT[128][64] @32768
__global__ void prep_weights(const float* __restrict__ qkvw, const float* __restrict__ wo,
                             const float* __restrict__ w1, const float* __restrict__ w2,
                             const float* __restrict__ pw, u16* __restrict__ wt) {
    int i = blockIdx.x * 256 + threadIdx.x;
    if (i < 12288)      { int n = i >> 6, k = i & 63;                wt[i] = f2b(qkvw[k * 192 + n]); }
    else if (i < 16384) { int j = i - 12288; int n = j >> 6, k = j & 63;  wt[i] = f2b(wo[k * 64 + n]); }
    else if (i < 24576) { int j = i - 16384; int n = j >> 6, k = j & 63;  wt[i] = f2b(w1[k * 128 + n]); }
    else if (i < 32768) { int j = i - 24576; int n = j >> 7, k = j & 127; wt[i] = f2b(w2[k * 64 + n]); }
    else if (i < 40960) { int j = i - 32768; int n = j >> 6, k = j & 63;  wt[i] = f2b(pw[k * 128 + n]); }
}

// LDS (u16 idx):
//  R0 8192: xn [128][64] swizzled -> V^T [64][128] swizzled -> pooled [16][64] swizzled
//  R1 9216: Q [128][72] (pair-packed cols) -> P per-wave pack (wv*1152) -> x2n -> h-low
//  R2 9216: K [128][72] (pair-packed cols) -> O -> h-high.   h: [128][136] @ SHA=R1A.
// 26624 u16 = 53248 B -> 3 blocks/CU; 8 waves/block -> 24 waves/CU.
// Every tenant is own-wave-band (wave wv <-> rows [wv*16, wv*16+16)); 3 barriers total.
#define R0A 0
#define R1A 8192
#define R2A 17408
#define SHA 8192
#define SMEM_U16 26624

__global__ __launch_bounds__(512, 6)
void enc_mfma(const int* __restrict__ tokens, const int* __restrict__ lengths,
              const float* __restrict__ emb,
              const float* __restrict__ n1w, const float* __restrict__ n2w,
              const float* __restrict__ nw, const float* __restrict__ pb,
              const u16* __restrict__ wt, float* __restrict__ out) {
    __shared__ __align__(16) u16 s16[SMEM_U16];

    const int tid = threadIdx.x;
    const int l   = tid & 63;
    const int wv  = tid >> 6;           // 0..7, owns rows [wv*16, wv*16+16)
    const int lr  = l & 15;
    const int lk  = l >> 4;
    const int p0  = blockIdx.x << 4;
    const int rowb = wv * 16;           // wave's row base

    // ---------- Ph0: embed gather + rmsnorm1 -> R0 (swizzled bf16) ----------
    // thread -> row tid>>2 (own wave's band: tids [wv*64,..) -> rows [wv*16,..)), quarter tid&3
    {
        const int r = tid >> 2, q4 = tid & 3;
        const int tok = tokens[p0 * 8 + r];
        const float* er = emb + (size_t)tok * 64 + q4 * 16;
        float xv[16];
        #pragma unroll
        for (int i = 0; i < 4; ++i) {
            float4 f = ((const float4*)er)[i];
            xv[4*i] = f.x; xv[4*i+1] = f.y; xv[4*i+2] = f.z; xv[4*i+3] = f.w;
        }
        float ss = 0.f;
        #pragma unroll
        for (int k = 0; k < 16; ++k) ss = fmaf(xv[k], xv[k], ss);
        ss += __shfl_xor(ss, 1);
        ss += __shfl_xor(ss, 2);
        const float rstd = frsq(ss * 0.015625f + EPS);
        const int key = r & 7;
        #pragma unroll
        for (int k = 0; k < 8; ++k) {
            const float a = xv[2*k]     * n1w[q4*16 + 2*k]     * rstd;
            const float b = xv[2*k + 1] * n1w[q4*16 + 2*k + 1] * rstd;
            const int chunk = q4*2 + (k >> 2);
            const int addr = r * 64 + ((chunk ^ key) << 3) + ((2*k) & 7);
            *(unsigned*)(s16 + addr) = f2b2(a, b);
        }
    }
    // xn own band written by own wave -> no barrier before afr load

    // rope tables for rows lk*4+r (token t = row&7; rowb multiple of 16 drops out)
    float csr[4], snr[4];
    {
        const float fr = exp2f((float)lr * (-13.287712379549449f / 15.f));
        #pragma unroll
        for (int r = 0; r < 4; ++r) {
            const float th = (float)((lk*4 + r) & 7) * fr;
            csr[r] = __cosf(th); snr[r] = __sinf(th);
        }
    }

    // ---------- Ph1: QKV GEMM + rope -> Q(R1), K(R2), V^T(R0 swizzled) ----------
    {
        v8bf afr[2];
        #pragma unroll
        for (int ks = 0; ks < 2; ++ks)
            afr[ks] = ldfrag(s16 + R0A + (rowb + lr) * 64 + (((ks*4 + lk) ^ (lr & 7)) << 3));
        __syncthreads();   // BARRIER A: all xn reads done before V^T overwrites R0

        #pragma unroll
        for (int j = 0; j < 4; ++j) {        // Q (j=0,1 = head), K (j=2,3)
            v8bf blo[2], bhi[2];
            #pragma unroll
            for (int ks = 0; ks < 2; ++ks) {
                blo[ks] = ldfrag(wt + ((2*j)     * 16 + lr) * 64 + ks*32 + lk*8);
                bhi[ks] = ldfrag(wt + ((2*j + 1) * 16 + lr) * 64 + ks*32 + lk*8);
            }
            const int isq = (j < 2) ? 1 : 0;
            const int head = isq ? j : (j - 2);
            const int dst = isq ? R1A : R2A;
            v4f lo = {0.f,0.f,0.f,0.f}, hi = {0.f,0.f,0.f,0.f};
            #pragma unroll
            for (int ks = 0; ks < 2; ++ks) {
                lo = MFMA(afr[ks], blo[ks], lo);
                hi = MFMA(afr[ks], bhi[ks], hi);
            }
            #pragma unroll
            for (int r = 0; r < 4; ++r) {
                const float c = csr[r], s = snr[r];
                float nlo = lo[r] * c - hi[r] * s;
                float nhi = lo[r] * s + hi[r] * c;
                if (isq) { nlo *= 0.17677669529663687f; nhi *= 0.17677669529663687f; }
                const int row = rowb + lk*4 + r;
                // pair-packed: (nlo,nhi) at cols (2*lr, 2*lr+1) within head block.
                // Legal: same k-permutation applied to Q and K leaves Q.K invariant.
                *(unsigned*)(s16 + dst + row*72 + head*32 + 2*lr) = f2b2(nlo, nhi);
            }
        }
        // V -> R0 as V^T[64][128], per-row 16-chunk XOR swizzle (key = d&15)
        #pragma unroll
        for (int ntl = 0; ntl < 4; ++ntl) {
            v8bf b[2];
            #pragma unroll
            for (int ks = 0; ks < 2; ++ks)
                b[ks] = ldfrag(wt + ((8 + ntl) * 16 + lr) * 64 + ks*32 + lk*8);
            v4f ac = {0.f,0.f,0.f,0.f};
            #pragma unroll
            for (int ks = 0; ks < 2; ++ks) ac = MFMA(afr[ks], b[ks], ac);
            #pragma unroll
            for (int r = 0; r < 4; ++r) {
                const int d = ntl*16 + lr;
                const int tok = rowb + lk*4 + r;
                s16[R0A + d*128 + (((tok >> 3) ^ (d & 15)) << 3) + (tok & 7)] = f2b(ac[r]);
            }
        }
    }
    // Q,K,V^T,P,O all own-wave produced/consumed -> no barrier through attention

    // ---------- Ph2a: QK^T + causal softmax -> P (R1, per-wave pack) ----------
    // wave handles units (h=0,g=wv), (h=1,g=wv)
    const int pbase = R1A + wv * 1152;
    float rsum[2][4];
    {
        v8bf aq[2], bk[2];
        #pragma unroll
        for (int h = 0; h < 2; ++h) {
            aq[h] = ldfrag(s16 + R1A + (rowb + lr)*72 + h*32 + lk*8);
            bk[h] = ldfrag(s16 + R2A + (rowb + lr)*72 + h*32 + lk*8);
        }
        #pragma unroll
        for (int h = 0; h < 2; ++h) {
            v4f zz = {0.f,0.f,0.f,0.f};
            v4f sc = MFMA(aq[h], bk[h], zz);
            #pragma unroll
            for (int r = 0; r < 4; ++r) {
                const int row = lk*4 + r;
                const bool valid = ((lr >> 3) == (row >> 3)) && ((lr & 7) <= (row & 7));
                float e = valid ? __expf(sc[r]) : 0.f;
                float sum = e;
                sum += __shfl_xor(sum, 1);
                sum += __shfl_xor(sum, 2);
                sum += __shfl_xor(sum, 4);
                sum += __shfl_xor(sum, 8);
                rsum[h][r] = frcp(sum);
                s16[pbase + h*512 + row*32 + lr] = f2b(e);
            }
        }
    }

    // ---------- Ph2b: PV -> O (R2, own band; clobbers own K, already consumed) ----------
    #pragma unroll
    for (int h = 0; h < 2; ++h) {
        v8bf ap = zfrag();
        if (lk < 2) ap = ldfrag(s16 + pbase + h*512 + lr*32 + lk*8);
        #pragma unroll
        for (int dl = 0; dl < 2; ++dl) {
            const int dt = h*2 + dl;
            v8bf bv = zfrag();
            if (lk < 2) bv = ldfrag(s16 + R0A + (dt*16 + lr)*128 + (((2*wv + lk) ^ lr) << 3));
            v4f zz = {0.f,0.f,0.f,0.f};
            v4f oc = MFMA(ap, bv, zz);
            #pragma unroll
            for (int r = 0; r < 4; ++r) {
                const int row = rowb + lk*4 + r;
                s16[R2A + row*72 + dt*16 + lr] = f2b(oc[r] * rsum[h][r]);
            }
        }
    }

    // ---------- Ph3: Wo GEMM + residual (emb re-gather) + norm2 -> x2n (R1 own band) ----------
    v4f x2[4];
    {
        v8bf ao[2];
        #pragma unroll
        for (int ks = 0; ks < 2; ++ks)
            ao[ks] = ldfrag(s16 + R2A + (rowb + lr)*72 + ks*32 + lk*8);
        int trow[4];
        #pragma unroll
        for (int r = 0; r < 4; ++r)
            trow[r] = tokens[p0*8 + rowb + lk*4 + r];
        #pragma unroll
        for (int nt = 0; nt < 4; ++nt)
            #pragma unroll
            for (int r = 0; r < 4; ++r)
                x2[nt][r] = emb[(size_t)trow[r] * 64 + nt*16 + lr];
        #pragma unroll
        for (int nt = 0; nt < 4; ++nt) {
            v8bf b[2];
            #pragma unroll
            for (int ks = 0; ks < 2; ++ks)
                b[ks] = ldfrag(wt + 12288 + (nt*16 + lr)*64 + ks*32 + lk*8);
            #pragma unroll
            for (int ks = 0; ks < 2; ++ks)
                x2[nt] = MFMA(ao[ks], b[ks], x2[nt]);
        }
        float ssq[4] = {0.f,0.f,0.f,0.f};
        #pragma unroll
        for (int nt = 0; nt < 4; ++nt)
            #pragma unroll
            for (int r = 0; r < 4; ++r) ssq[r] = fmaf(x2[nt][r], x2[nt][r], ssq[r]);
        #pragma unroll
        for (int r = 0; r < 4; ++r) {
            ssq[r] += __shfl_xor(ssq[r], 1);
            ssq[r] += __shfl_xor(ssq[r], 2);
            ssq[r] += __shfl_xor(ssq[r], 4);
            ssq[r] += __shfl_xor(ssq[r], 8);
            ssq[r] = frsq(ssq[r] * 0.015625f + EPS);
        }
        #pragma unroll
        for (int nt = 0; nt < 4; ++nt) {
            const float nv = n2w[nt*16 + lr];
            #pragma unroll
            for (int r = 0; r < 4; ++r) {
                const int row = rowb + lk*4 + r;
                s16[R1A + row*72 + nt*16 + lr] = f2b(x2[nt][r] * nv * ssq[r]);
            }
        }
    }

    // ---------- Ph4: FFN1 + silu -> h [128][136] spanning R1+R2 ----------
    {
        v8bf a[2];
        #pragma unroll
        for (int ks = 0; ks < 2; ++ks)
            a[ks] = ldfrag(s16 + R1A + (rowb + lr)*72 + ks*32 + lk*8);
        __syncthreads();   // BARRIER B: all pre-B reads (V^T, x2n, O, P) done before h overwrites
        #pragma unroll
        for (int nt = 0; nt < 8; ++nt) {
            v8bf b[2];
            #pragma unroll
            for (int ks = 0; ks < 2; ++ks)
                b[ks] = ldfrag(wt + 16384 + (nt*16 + lr)*64 + ks*32 + lk*8);
            v4f hc = {0.f,0.f,0.f,0.f};
            #pragma unroll
            for (int ks = 0; ks < 2; ++ks) hc = MFMA(a[ks], b[ks], hc);
            #pragma unroll
            for (int r = 0; r < 4; ++r) {
                const float v = hc[r];
                const float sl = v * frcp(1.f + __expf(-v));
                const int row = rowb + lk*4 + r;
                s16[SHA + row*136 + nt*16 + lr] = f2b(sl);
            }
        }
    }

    // ---------- Ph5: FFN2 (C-in = x2) + norm3 + masked mean pool -> pooled (R0) ----------
    {
        v8bf a2[4];
        #pragma unroll
        for (int ks = 0; ks < 4; ++ks)
            a2[ks] = ldfrag(s16 + SHA + (rowb + lr)*136 + ks*32 + lk*8);
        #pragma unroll
        for (int nt = 0; nt < 4; ++nt) {
            v8bf b[4];
            #pragma unroll
            for (int ks = 0; ks < 4; ++ks)
                b[ks] = ldfrag(wt + 24576 + (nt*16 + lr)*128 + ks*32 + lk*8);
            #pragma unroll
            for (int ks = 0; ks < 4; ++ks)
                x2[nt] = MFMA(a2[ks], b[ks], x2[nt]);
        }
        float ssq[4] = {0.f,0.f,0.f,0.f};
        #pragma unroll
        for (int nt = 0; nt < 4; ++nt)
            #pragma unroll
            for (int r = 0; r < 4; ++r) ssq[r] = fmaf(x2[nt][r], x2[nt][r], ssq[r]);
        #pragma unroll
        for (int r = 0; r < 4; ++r) {
            ssq[r] += __shfl_xor(ssq[r], 1);
            ssq[r] += __shfl_xor(ssq[r], 2);
            ssq[r] += __shfl_xor(ssq[r], 4);
            ssq[r] += __shfl_xor(ssq[r], 8);
            ssq[r] = frsq(ssq[r] * 0.015625f + EPS);
        }
        const int lp = wv*2 + (lk >> 1);
        const int len = lengths[p0 + lp];
        const float invl = frcp((float)len);
        #pragma unroll
        for (int nt = 0; nt < 4; ++nt) {
            const float nv = nw[nt*16 + lr];
            float part = 0.f;
            #pragma unroll
            for (int r = 0; r < 4; ++r) {
                const int tt = (lk & 1) * 4 + r;
                const float xn3 = x2[nt][r] * nv * ssq[r];
                part += (tt < len) ? xn3 : 0.f;
            }
            part += __shfl_xor(part, 16);
            if ((lk & 1) == 0) {
                const int addr = R0A + lp*64
                    + (((2*nt + (lr >> 3)) ^ (lp & 7)) << 3) + (lr & 7);
                s16[addr] = f2b(part * invl);
            }
        }
    }
    __syncthreads();   // BARRIER C: pooled visible to all waves

    // ---------- Ph6: proj [16x64]@[64x128] + bias -> out (wave wv does out-cols wv*16..) ----------
    {
        v8bf ap2[2];
        #pragma unroll
        for (int ks = 0; ks < 2; ++ks)
            ap2[ks] = ldfrag(s16 + R0A + lr*64 + (((ks*4 + lk) ^ (lr & 7)) << 3));
        v8bf b[2];
        #pragma unroll
        for (int ks = 0; ks < 2; ++ks)
            b[ks] = ldfrag(wt + 32768 + (wv*16 + lr)*64 + ks*32 + lk*8);
        const float bias = pb[wv*16 + lr];
        v4f ac = {bias, bias, bias, bias};
        #pragma unroll
        for (int ks = 0; ks < 2; ++ks) ac = MFMA(ap2[ks], b[ks], ac);
        #pragma unroll
        for (int r = 0; r < 4; ++r)
            out[(size_t)(p0 + lk*4 + r) * 128 + wv*16 + lr] = ac[r];
    }
}

extern "C" void kernel_launch(void* const* d_in, const int* in_sizes, int n_in,
                              void* d_out, int out_size, void* d_ws, size_t ws_size,
                              hipStream_t stream) {
    const int*   tokens  = (const int*)  d_in[0];
    const int*   lengths = (const int*)  d_in[1];
    const float* emb     = (const float*)d_in[2];
    const float* qkvw    = (const float*)d_in[3];
    const float* wo      = (const float*)d_in[4];
    const float* n1w     = (const float*)d_in[5];
    const float* n2w     = (const float*)d_in[6];
    const float* w1      = (const float*)d_in[7];
    const float* w2      = (const float*)d_in[8];
    const float* nw      = (const float*)d_in[9];
    const float* pw      = (const float*)d_in[10];
    const float* pb      = (const float*)d_in[11];
    float* outp = (float*)d_out;
    u16* wt = (u16*)d_ws;

    hipLaunchKernelGGL(prep_weights, dim3(160), dim3(256), 0, stream,
                       qkvw, wo, w1, w2, pw, wt);
    hipLaunchKernelGGL(enc_mfma, dim3(NP / 16), dim3(512), 0, stream,
                       tokens, lengths, emb, n1w, n2w, nw, pb, (const u16*)wt, outp);
}

// Round 7
// 395.352 us; speedup vs baseline: 1.5258x; 1.5258x over previous
//
#include <hip/hip_runtime.h>
#include <math.h>

#define NP 131072

typedef unsigned short u16;
typedef __bf16 v8bf __attribute__((ext_vector_type(8)));
typedef unsigned v4u __attribute__((ext_vector_type(4)));
typedef float v4f __attribute__((ext_vector_type(4)));

#define MFMA(a, b, c) __builtin_amdgcn_mfma_f32_16x16x32_bf16(a, b, c, 0, 0, 0)
#define EPS 1.1920928955078125e-07f

__device__ __forceinline__ u16 f2b(float f) { return __builtin_bit_cast(u16, (__bf16)f); }
__device__ __forceinline__ unsigned f2b2(float a, float b) {
    return (unsigned)f2b(a) | ((unsigned)f2b(b) << 16);
}
__device__ __forceinline__ float frcp(float x) { return __builtin_amdgcn_rcpf(x); }
__device__ __forceinline__ float frsq(float x) { return __builtin_amdgcn_rsqf(x); }
__device__ __forceinline__ v8bf ldfrag(const u16* p) { return *(const v8bf*)p; }
__device__ __forceinline__ v8bf zfrag() { v4u z = {0,0,0,0}; return __builtin_bit_cast(v8bf, z); }

// ---- weight prep: transpose + bf16 into ws ----
// layout (u16): qkvT[192][64] @0 ; woT[64][64] @12288 ; w1T[128][64] @16384 ;
//               w2T[64][128] @24576 ; projT[128][64] @32768
__global__ void prep_weights(const float* __restrict__ qkvw, const float* __restrict__ wo,
                             const float* __restrict__ w1, const float* __restrict__ w2,
                             const float* __restrict__ pw, u16* __restrict__ wt) {
    int i = blockIdx.x * 256 + threadIdx.x;
    if (i < 12288)      { int n = i >> 6, k = i & 63;                wt[i] = f2b(qkvw[k * 192 + n]); }
    else if (i < 16384) { int j = i - 12288; int n = j >> 6, k = j & 63;  wt[i] = f2b(wo[k * 64 + n]); }
    else if (i < 24576) { int j = i - 16384; int n = j >> 6, k = j & 63;  wt[i] = f2b(w1[k * 128 + n]); }
    else if (i < 32768) { int j = i - 24576; int n = j >> 7, k = j & 127; wt[i] = f2b(w2[k * 64 + n]); }
    else if (i < 40960) { int j = i - 32768; int n = j >> 6, k = j & 63;  wt[i] = f2b(pw[k * 128 + n]); }
}

// LDS (u16 idx), 19456 u16 = 38912 B -> 4 blocks/CU, 16 waves/CU:
//  QA 0..9216:    xn [128][72] swz -> Q [128][72] pair-packed -> P (wv*2304 pack) -> x2n
//  KA 9216..18432: K [128][72] pair-packed -> O
//  SHA 0:         h [128][136] overlays QA+KA (barrier B protects)
//  PO 18432..19456: pooled [16][64] swz
// V never touches LDS (kept in regs, PV B-frag built via __shfl).
// All tenants own-wave-band; 2 barriers total (B before h, C before proj).
#define QA 0
#define KA 9216
#define SHA 0
#define PO 18432
#define SMEM_U16 19456

__global__ __launch_bounds__(256, 4)
void enc_mfma(const int* __restrict__ tokens, const int* __restrict__ lengths,
              const float* __restrict__ emb,
              const float* __restrict__ n1w, const float* __restrict__ n2w,
              const float* __restrict__ nw, const float* __restrict__ pb,
              const u16* __restrict__ wt, float* __restrict__ out) {
    __shared__ __align__(16) u16 s16[SMEM_U16];

    const int tid = threadIdx.x;
    const int l   = tid & 63;
    const int wv  = tid >> 6;           // 0..3, owns rows [wv*32, wv*32+32)
    const int lr  = l & 15;
    const int lk  = l >> 4;
    const int p0  = blockIdx.x << 4;

    // ---------- Ph0: embed gather + rmsnorm1 -> xn in QA (swizzled, stride 72) ----------
    {
        const int r = tid >> 1, hh = tid & 1;    // wave covers own rows [32wv,32wv+32)
        const int tok = tokens[p0 * 8 + r];
        const float* er = emb + (size_t)tok * 64 + hh * 32;
        float xv[32];
        #pragma unroll
        for (int i = 0; i < 8; ++i) {
            float4 f = ((const float4*)er)[i];
            xv[4*i] = f.x; xv[4*i+1] = f.y; xv[4*i+2] = f.z; xv[4*i+3] = f.w;
        }
        float ss = 0.f;
        #pragma unroll
        for (int k = 0; k < 32; ++k) ss = fmaf(xv[k], xv[k], ss);
        ss += __shfl_xor(ss, 1);
        const float rstd = frsq(ss * 0.015625f + EPS);
        const int key = r & 7;
        #pragma unroll
        for (int k = 0; k < 16; ++k) {
            const float a = xv[2*k]     * n1w[hh*32 + 2*k]     * rstd;
            const float b = xv[2*k + 1] * n1w[hh*32 + 2*k + 1] * rstd;
            const int addr = QA + r * 72 + (((hh*4 + (k >> 2)) ^ key) << 3) + ((2*k) & 7);
            *(unsigned*)(s16 + addr) = f2b2(a, b);
        }
    }
    // xn: own band written/read by own wave -> no barrier

    // rope tables for rows lk*4+r (token t = row&7)
    float csr[4], snr[4];
    {
        const float fr = exp2f((float)lr * (-13.287712379549449f / 15.f));
        #pragma unroll
        for (int r = 0; r < 4; ++r) {
            const float th = (float)((lk*4 + r) & 7) * fr;
            csr[r] = __cosf(th); snr[r] = __sinf(th);
        }
    }

    // V kept in registers: vpk[dt][mi] = 4 bf16 pairs (tokens lk*4+{0..3} at d=dt*16+lr)
    unsigned vpx[4][2], vpy[4][2];

    // ---------- Ph1: QKV GEMM + rope -> Q(QA), K(KA) pair-packed; V -> regs ----------
    {
        v8bf afr[2][2];
        #pragma unroll
        for (int mi = 0; mi < 2; ++mi)
            #pragma unroll
            for (int ks = 0; ks < 2; ++ks)
                afr[mi][ks] = ldfrag(s16 + QA + (wv*32 + mi*16 + lr) * 72
                                     + (((ks*4 + lk) ^ (lr & 7)) << 3));

        #pragma unroll
        for (int j = 0; j < 4; ++j) {        // Q (j=0,1 = head), K (j=2,3)
            v8bf blo[2], bhi[2];
            #pragma unroll
            for (int ks = 0; ks < 2; ++ks) {
                blo[ks] = ldfrag(wt + ((2*j)     * 16 + lr) * 64 + ks*32 + lk*8);
                bhi[ks] = ldfrag(wt + ((2*j + 1) * 16 + lr) * 64 + ks*32 + lk*8);
            }
            const int isq = (j < 2) ? 1 : 0;
            const int head = isq ? j : (j - 2);
            const int dst = isq ? QA : KA;
            #pragma unroll
            for (int mi = 0; mi < 2; ++mi) {
                v4f lo = {0.f,0.f,0.f,0.f}, hi = {0.f,0.f,0.f,0.f};
                #pragma unroll
                for (int ks = 0; ks < 2; ++ks) {
                    lo = MFMA(afr[mi][ks], blo[ks], lo);
                    hi = MFMA(afr[mi][ks], bhi[ks], hi);
                }
                #pragma unroll
                for (int r = 0; r < 4; ++r) {
                    const float c = csr[r], s = snr[r];
                    float nlo = lo[r] * c - hi[r] * s;
                    float nhi = lo[r] * s + hi[r] * c;
                    if (isq) { nlo *= 0.17677669529663687f; nhi *= 0.17677669529663687f; }
                    const int row = wv*32 + mi*16 + lk*4 + r;
                    // pair-packed (k-permutation applied to both Q and K -> dot invariant)
                    *(unsigned*)(s16 + dst + row*72 + head*32 + 2*lr) = f2b2(nlo, nhi);
                }
            }
        }
        // V tiles -> registers (bf16-packed C-fragments)
        #pragma unroll
        for (int ntl = 0; ntl < 4; ++ntl) {
            v8bf b[2];
            #pragma unroll
            for (int ks = 0; ks < 2; ++ks)
                b[ks] = ldfrag(wt + ((8 + ntl) * 16 + lr) * 64 + ks*32 + lk*8);
            #pragma unroll
            for (int mi = 0; mi < 2; ++mi) {
                v4f ac = {0.f,0.f,0.f,0.f};
                #pragma unroll
                for (int ks = 0; ks < 2; ++ks) ac = MFMA(afr[mi][ks], b[ks], ac);
                vpx[ntl][mi] = f2b2(ac[0], ac[1]);
                vpy[ntl][mi] = f2b2(ac[2], ac[3]);
            }
        }
    }
    // Q,K,P,O own-wave produced/consumed -> no barrier through attention

    // ---------- Ph2a: QK^T + causal softmax -> P (QA, per-wave pack) ----------
    // unit uu: h = uu>>1, g = 2*wv + (uu&1)
    const int pbase = QA + wv * 2304;
    float rsum[4][4];
    {
        v8bf aq[4], bk[4];
        #pragma unroll
        for (int uu = 0; uu < 4; ++uu) {
            const int h = uu >> 1, g = 2*wv + (uu & 1);
            aq[uu] = ldfrag(s16 + QA + (g*16 + lr)*72 + h*32 + lk*8);
            bk[uu] = ldfrag(s16 + KA + (g*16 + lr)*72 + h*32 + lk*8);
        }
        #pragma unroll
        for (int uu = 0; uu < 4; ++uu) {
            v4f zz = {0.f,0.f,0.f,0.f};
            v4f sc = MFMA(aq[uu], bk[uu], zz);
            #pragma unroll
            for (int r = 0; r < 4; ++r) {
                const int row = lk*4 + r;
                const bool valid = ((lr >> 3) == (row >> 3)) && ((lr & 7) <= (row & 7));
                float e = valid ? __expf(sc[r]) : 0.f;
                float sum = e;
                sum += __shfl_xor(sum, 1);
                sum += __shfl_xor(sum, 2);
                sum += __shfl_xor(sum, 4);
                sum += __shfl_xor(sum, 8);
                rsum[uu][r] = frcp(sum);
                s16[pbase + uu*512 + row*32 + lr] = f2b(e);
            }
        }
    }

    // ---------- Ph2b: PV -> O (KA, own band); V B-frag built by __shfl from vpk ----------
    {
        const int s0 = lr + ((lk & 1) << 5);   // source lanes (valid for lk<2)
        const int s1 = s0 + 16;
        #pragma unroll
        for (int uu = 0; uu < 4; ++uu) {
            const int mw = uu & 1, g = 2*wv + mw;
            v8bf ap = zfrag();
            if (lk < 2) ap = ldfrag(s16 + pbase + uu*512 + lr*32 + lk*8);
            #pragma unroll
            for (int dl = 0; dl < 2; ++dl) {
                const int dt = (uu >> 1)*2 + dl;
                v4u bw;
                bw[0] = __shfl(vpx[dt][mw], s0);
                bw[1] = __shfl(vpy[dt][mw], s0);
                bw[2] = __shfl(vpx[dt][mw], s1);
                bw[3] = __shfl(vpy[dt][mw], s1);
                if (lk >= 2) { bw[0] = 0; bw[1] = 0; bw[2] = 0; bw[3] = 0; }
                v8bf bv = __builtin_bit_cast(v8bf, bw);
                v4f zz = {0.f,0.f,0.f,0.f};
                v4f oc = MFMA(ap, bv, zz);
                #pragma unroll
                for (int r = 0; r < 4; ++r) {
                    const int row = g*16 + lk*4 + r;
                    s16[KA + row*72 + dt*16 + lr] = f2b(oc[r] * rsum[uu][r]);
                }
            }
        }
    }

    // ---------- Ph3: Wo GEMM + residual (emb re-gather) + norm2 -> x2n (QA own band) ----------
    v4f x2[2][4];
    {
        v8bf ao[2][2];
        #pragma unroll
        for (int mi = 0; mi < 2; ++mi)
            #pragma unroll
            for (int ks = 0; ks < 2; ++ks)
                ao[mi][ks] = ldfrag(s16 + KA + (wv*32 + mi*16 + lr)*72 + ks*32 + lk*8);
        int trow[2][4];
        #pragma unroll
        for (int mi = 0; mi < 2; ++mi)
            #pragma unroll
            for (int r = 0; r < 4; ++r)
                trow[mi][r] = tokens[p0*8 + wv*32 + mi*16 + lk*4 + r];
        #pragma unroll
        for (int mi = 0; mi < 2; ++mi)
            #pragma unroll
            for (int nt = 0; nt < 4; ++nt)
                #pragma unroll
                for (int r = 0; r < 4; ++r)
                    x2[mi][nt][r] = emb[(size_t)trow[mi][r] * 64 + nt*16 + lr];
        #pragma unroll
        for (int nt = 0; nt < 4; ++nt) {
            v8bf b[2];
            #pragma unroll
            for (int ks = 0; ks < 2; ++ks)
                b[ks] = ldfrag(wt + 12288 + (nt*16 + lr)*64 + ks*32 + lk*8);
            #pragma unroll
            for (int mi = 0; mi < 2; ++mi)
                #pragma unroll
                for (int ks = 0; ks < 2; ++ks)
                    x2[mi][nt] = MFMA(ao[mi][ks], b[ks], x2[mi][nt]);
        }
        #pragma unroll
        for (int mi = 0; mi < 2; ++mi) {
            float ssq[4] = {0.f,0.f,0.f,0.f};
            #pragma unroll
            for (int nt = 0; nt < 4; ++nt)
                #pragma unroll
                for (int r = 0; r < 4; ++r) ssq[r] = fmaf(x2[mi][nt][r], x2[mi][nt][r], ssq[r]);
            #pragma unroll
            for (int r = 0; r < 4; ++r) {
                ssq[r] += __shfl_xor(ssq[r], 1);
                ssq[r] += __shfl_xor(ssq[r], 2);
                ssq[r] += __shfl_xor(ssq[r], 4);
                ssq[r] += __shfl_xor(ssq[r], 8);
                ssq[r] = frsq(ssq[r] * 0.015625f + EPS);
            }
            #pragma unroll
            for (int nt = 0; nt < 4; ++nt) {
                const float nv = n2w[nt*16 + lr];
                #pragma unroll
                for (int r = 0; r < 4; ++r) {
                    const int row = wv*32 + mi*16 + lk*4 + r;
                    s16[QA + row*72 + nt*16 + lr] = f2b(x2[mi][nt][r] * nv * ssq[r]);
                }
            }
        }
    }

    // ---------- Ph4: FFN1 + silu -> h [128][136] overlaying QA+KA ----------
    {
        v8bf a[2][2];
        #pragma unroll
        for (int mi = 0; mi < 2; ++mi)
            #pragma unroll
            for (int ks = 0; ks < 2; ++ks)
                a[mi][ks] = ldfrag(s16 + QA + (wv*32 + mi*16 + lr)*72 + ks*32 + lk*8);
        __syncthreads();   // BARRIER B: all x2n/O/P reads done before h overwrites QA+KA
        #pragma unroll
        for (int nt = 0; nt < 8; ++nt) {
            v8bf b[2];
            #pragma unroll
            for (int ks = 0; ks < 2; ++ks)
                b[ks] = ldfrag(wt + 16384 + (nt*16 + lr)*64 + ks*32 + lk*8);
            #pragma unroll
            for (int mi = 0; mi < 2; ++mi) {
                v4f hc = {0.f,0.f,0.f,0.f};
                #pragma unroll
                for (int ks = 0; ks < 2; ++ks) hc = MFMA(a[mi][ks], b[ks], hc);
                #pragma unroll
                for (int r = 0; r < 4; ++r) {
                    const float v = hc[r];
                    const float sl = v * frcp(1.f + __expf(-v));
                    const int row = wv*32 + mi*16 + lk*4 + r;
                    s16[SHA + row*136 + nt*16 + lr] = f2b(sl);
                }
            }
        }
    }

    // ---------- Ph5: FFN2 (C-in = x2) + norm3 + masked mean pool -> pooled (PO) ----------
    {
        v8bf a2[2][4];
        #pragma unroll
        for (int mi = 0; mi < 2; ++mi)
            #pragma unroll
            for (int ks = 0; ks < 4; ++ks)
                a2[mi][ks] = ldfrag(s16 + SHA + (wv*32 + mi*16 + lr)*136 + ks*32 + lk*8);
        #pragma unroll
        for (int nt = 0; nt < 4; ++nt) {
            v8bf b[4];
            #pragma unroll
            for (int ks = 0; ks < 4; ++ks)
                b[ks] = ldfrag(wt + 24576 + (nt*16 + lr)*128 + ks*32 + lk*8);
            #pragma unroll
            for (int mi = 0; mi < 2; ++mi)
                #pragma unroll
                for (int ks = 0; ks < 4; ++ks)
                    x2[mi][nt] = MFMA(a2[mi][ks], b[ks], x2[mi][nt]);
        }
        #pragma unroll
        for (int mi = 0; mi < 2; ++mi) {
            float ssq[4] = {0.f,0.f,0.f,0.f};
            #pragma unroll
            for (int nt = 0; nt < 4; ++nt)
                #pragma unroll
                for (int r = 0; r < 4; ++r) ssq[r] = fmaf(x2[mi][nt][r], x2[mi][nt][r], ssq[r]);
            #pragma unroll
            for (int r = 0; r < 4; ++r) {
                ssq[r] += __shfl_xor(ssq[r], 1);
                ssq[r] += __shfl_xor(ssq[r], 2);
                ssq[r] += __shfl_xor(ssq[r], 4);
                ssq[r] += __shfl_xor(ssq[r], 8);
                ssq[r] = frsq(ssq[r] * 0.015625f + EPS);
            }
            const int lp = wv*4 + mi*2 + (lk >> 1);
            const int len = lengths[p0 + lp];
            const float invl = frcp((float)len);
            #pragma unroll
            for (int nt = 0; nt < 4; ++nt) {
                const float nv = nw[nt*16 + lr];
                float part = 0.f;
                #pragma unroll
                for (int r = 0; r < 4; ++r) {
                    const int tt = (lk & 1) * 4 + r;
                    const float xn3 = x2[mi][nt][r] * nv * ssq[r];
                    part += (tt < len) ? xn3 : 0.f;
                }
                part += __shfl_xor(part, 16);
                if ((lk & 1) == 0) {
                    const int addr = PO + lp*64
                        + (((2*nt + (lr >> 3)) ^ (lp & 7)) << 3) + (lr & 7);
                    s16[addr] = f2b(part * invl);
                }
            }
        }
    }
    __syncthreads();   // BARRIER C: pooled visible to all waves

    // ---------- Ph6: proj [16x64]@[64x128] + bias -> out ----------
    {
        v8bf ap2[2];
        #pragma unroll
        for (int ks = 0; ks < 2; ++ks)
            ap2[ks] = ldfrag(s16 + PO + lr*64 + (((ks*4 + lk) ^ (lr & 7)) << 3));
        #pragma unroll
        for (int ntl = 0; ntl < 2; ++ntl) {
            const int nt = wv*2 + ntl;
            v8bf b[2];
            #pragma unroll
            for (int ks = 0; ks < 2; ++ks)
                b[ks] = ldfrag(wt + 32768 + (nt*16 + lr)*64 + ks*32 + lk*8);
            const float bias = pb[nt*16 + lr];
            v4f ac = {bias, bias, bias, bias};
            #pragma unroll
            for (int ks = 0; ks < 2; ++ks) ac = MFMA(ap2[ks], b[ks], ac);
            #pragma unroll
            for (int r = 0; r < 4; ++r)
                out[(size_t)(p0 + lk*4 + r) * 128 + nt*16 + lr] = ac[r];
        }
    }
}

extern "C" void kernel_launch(void* const* d_in, const int* in_sizes, int n_in,
                              void* d_out, int out_size, void* d_ws, size_t ws_size,
                              hipStream_t stream) {
    const int*   tokens  = (const int*)  d_in[0];
    const int*   lengths = (const int*)  d_in[1];
    const float* emb     = (const float*)d_in[2];
    const float* qkvw    = (const float*)d_in[3];
    const float* wo      = (const float*)d_in[4];
    const float* n1w     = (const float*)d_in[5];
    const float* n2w     = (const float*)d_in[6];
    const float* w1      = (const float*)d_in[7];
    const float* w2      = (const float*)d_in[8];
    const float* nw      = (const float*)d_in[9];
    const float* pw      = (const float*)d_in[10];
    const float* pb      = (const float*)d_in[11];
    float* outp = (float*)d_out;
    u16* wt = (u16*)d_ws;

    hipLaunchKernelGGL(prep_weights, dim3(160), dim3(256), 0, stream,
                       qkvw, wo, w1, w2, pw, wt);
    hipLaunchKernelGGL(enc_mfma, dim3(NP / 16), dim3(256), 0, stream,
                       tokens, lengths, emb, n1w, n2w, nw, pb, (const u16*)wt, outp);
}

// Round 8
// 321.683 us; speedup vs baseline: 1.8753x; 1.2290x over previous
//
#include <hip/hip_runtime.h>
#include <math.h>

#define NP 131072

typedef unsigned short u16;
typedef __bf16 v8bf __attribute__((ext_vector_type(8)));
typedef unsigned v4u __attribute__((ext_vector_type(4)));
typedef float v4f __attribute__((ext_vector_type(4)));

#define MFMA(a, b, c) __builtin_amdgcn_mfma_f32_16x16x32_bf16(a, b, c, 0, 0, 0)
#define EPS 1.1920928955078125e-07f

__device__ __forceinline__ u16 f2b(float f) { return __builtin_bit_cast(u16, (__bf16)f); }
__device__ __forceinline__ unsigned f2b2(float a, float b) {
    return (unsigned)f2b(a) | ((unsigned)f2b(b) << 16);
}
__device__ __forceinline__ float b2f(u16 u) {
    unsigned v = (unsigned)u << 16; return __builtin_bit_cast(float, v);
}
__device__ __forceinline__ float frcp(float x) { return __builtin_amdgcn_rcpf(x); }
__device__ __forceinline__ float frsq(float x) { return __builtin_amdgcn_rsqf(x); }
__device__ __forceinline__ v8bf ldfrag(const u16* p) { return *(const v8bf*)p; }
__device__ __forceinline__ v8bf zfrag() { v4u z = {0,0,0,0}; return __builtin_bit_cast(v8bf, z); }

// ---- weight prep: transpose + bf16 into ws ----
// layout (u16): qkvT[192][64] @0 ; woT[64][64] @12288 ; w1T[128][64] @16384 ;
//               w2T[64][128] @24576 ; projT[128][64] @32768
__global__ void prep_weights(const float* __restrict__ qkvw, const float* __restrict__ wo,
                             const float* __restrict__ w1, const float* __restrict__ w2,
                             const float* __restrict__ pw, u16* __restrict__ wt) {
    int i = blockIdx.x * 256 + threadIdx.x;
    if (i < 12288)      { int n = i >> 6, k = i & 63;                wt[i] = f2b(qkvw[k * 192 + n]); }
    else if (i < 16384) { int j = i - 12288; int n = j >> 6, k = j & 63;  wt[i] = f2b(wo[k * 64 + n]); }
    else if (i < 24576) { int j = i - 16384; int n = j >> 6, k = j & 63;  wt[i] = f2b(w1[k * 128 + n]); }
    else if (i < 32768) { int j = i - 24576; int n = j >> 7, k = j & 127; wt[i] = f2b(w2[k * 64 + n]); }
    else if (i < 40960) { int j = i - 32768; int n = j >> 6, k = j & 63;  wt[i] = f2b(pw[k * 128 + n]); }
}

// 32 patches/block (256 rows). Wave wv owns rows [wv*64, wv*64+64) = 4 M-tiles.
// LDS (u16 idx), 38912 u16 = 77824 B -> 2 blocks/CU:
//  QA 0..18432:     xn [256][72] swz -> Q pair-packed -> P (pbase=wv*4608, 8x512) -> x2n
//  KA 18432..36864: K [256][72] pair-packed -> O
//  SHA 0:           h [256][136] overlays QA+KA (barrier B)
//  PO 36864..38912: pooled [32][64] swz
// V in regs (vpx/vpy[4][4]); PV B-frag via __shfl. 2 barriers (B, C).
#define QA 0
#define KA 18432
#define SHA 0
#define PO 36864
#define SMEM_U16 38912

__global__ __launch_bounds__(256, 2)
void enc_mfma(const int* __restrict__ tokens, const int* __restrict__ lengths,
              const float* __restrict__ emb,
              const float* __restrict__ n1w, const float* __restrict__ n2w,
              const float* __restrict__ nw, const float* __restrict__ pb,
              const u16* __restrict__ wt, float* __restrict__ out) {
    __shared__ __align__(16) u16 s16[SMEM_U16];

    const int tid = threadIdx.x;
    const int l   = tid & 63;
    const int wv  = tid >> 6;           // 0..3, owns rows [wv*64, wv*64+64)
    const int lr  = l & 15;
    const int lk  = l >> 4;
    const int p0  = blockIdx.x << 5;    // 32 patches

    // ---------- Ph0: embed gather + rmsnorm1 -> xn in QA (one full row per thread) ----------
    {
        const int r = tid;              // row 0..255; rows [wv*64,..) belong to own wave
        const int tok = tokens[p0 * 8 + r];
        const float* er = emb + (size_t)tok * 64;
        float xv[64];
        #pragma unroll
        for (int i = 0; i < 16; ++i) {
            float4 f = ((const float4*)er)[i];
            xv[4*i] = f.x; xv[4*i+1] = f.y; xv[4*i+2] = f.z; xv[4*i+3] = f.w;
        }
        float ss = 0.f;
        #pragma unroll
        for (int k = 0; k < 64; ++k) ss = fmaf(xv[k], xv[k], ss);
        const float rstd = frsq(ss * 0.015625f + EPS);
        const int key = r & 7;
        #pragma unroll
        for (int k = 0; k < 32; ++k) {
            const float a = xv[2*k]     * n1w[2*k]     * rstd;
            const float b = xv[2*k + 1] * n1w[2*k + 1] * rstd;
            const int addr = QA + r * 72 + (((k >> 2) ^ key) << 3) + ((2*k) & 7);
            *(unsigned*)(s16 + addr) = f2b2(a, b);
        }
    }

    // rope tables for rows lk*4+r (token t = row&7; mi*16, wv*64 drop out mod 8)
    float csr[4], snr[4];
    {
        const float fr = exp2f((float)lr * (-13.287712379549449f / 15.f));
        #pragma unroll
        for (int r = 0; r < 4; ++r) {
            const float th = (float)((lk*4 + r) & 7) * fr;
            csr[r] = __cosf(th); snr[r] = __sinf(th);
        }
    }

    // V in regs: vpx/vpy[dt][mi] = bf16 pairs (tokens lk*4+{0,1}/{2,3} at d=dt*16+lr)
    unsigned vpx[4][4], vpy[4][4];

    // ---------- Ph1: QKV GEMM + rope -> Q(QA), K(KA) pair-packed; V -> regs ----------
    {
        v8bf afr[4][2];
        #pragma unroll
        for (int mi = 0; mi < 4; ++mi)
            #pragma unroll
            for (int ks = 0; ks < 2; ++ks)
                afr[mi][ks] = ldfrag(s16 + QA + (wv*64 + mi*16 + lr) * 72
                                     + (((ks*4 + lk) ^ (lr & 7)) << 3));

        #pragma unroll
        for (int j = 0; j < 4; ++j) {        // Q (j=0,1 = head), K (j=2,3)
            v8bf blo[2], bhi[2];
            #pragma unroll
            for (int ks = 0; ks < 2; ++ks) {
                blo[ks] = ldfrag(wt + ((2*j)     * 16 + lr) * 64 + ks*32 + lk*8);
                bhi[ks] = ldfrag(wt + ((2*j + 1) * 16 + lr) * 64 + ks*32 + lk*8);
            }
            const int isq = (j < 2) ? 1 : 0;
            const int head = isq ? j : (j - 2);
            const int dst = isq ? QA : KA;
            #pragma unroll
            for (int mi = 0; mi < 4; ++mi) {
                v4f lo = {0.f,0.f,0.f,0.f}, hi = {0.f,0.f,0.f,0.f};
                #pragma unroll
                for (int ks = 0; ks < 2; ++ks) {
                    lo = MFMA(afr[mi][ks], blo[ks], lo);
                    hi = MFMA(afr[mi][ks], bhi[ks], hi);
                }
                #pragma unroll
                for (int r = 0; r < 4; ++r) {
                    const float c = csr[r], s = snr[r];
                    float nlo = lo[r] * c - hi[r] * s;
                    float nhi = lo[r] * s + hi[r] * c;
                    if (isq) { nlo *= 0.17677669529663687f; nhi *= 0.17677669529663687f; }
                    const int row = wv*64 + mi*16 + lk*4 + r;
                    *(unsigned*)(s16 + dst + row*72 + head*32 + 2*lr) = f2b2(nlo, nhi);
                }
            }
        }
        #pragma unroll
        for (int ntl = 0; ntl < 4; ++ntl) {
            v8bf b[2];
            #pragma unroll
            for (int ks = 0; ks < 2; ++ks)
                b[ks] = ldfrag(wt + ((8 + ntl) * 16 + lr) * 64 + ks*32 + lk*8);
            #pragma unroll
            for (int mi = 0; mi < 4; ++mi) {
                v4f ac = {0.f,0.f,0.f,0.f};
                #pragma unroll
                for (int ks = 0; ks < 2; ++ks) ac = MFMA(afr[mi][ks], b[ks], ac);
                vpx[ntl][mi] = f2b2(ac[0], ac[1]);
                vpy[ntl][mi] = f2b2(ac[2], ac[3]);
            }
        }
    }
    // Q,K,P,O own-wave produced/consumed -> no barrier through attention

    // ---------- Ph2a: QK^T + causal softmax -> P (QA, pbase own band) ----------
    // unit uu: h = uu>>2, g = 4*wv + (uu&3). P fits own 64-row Q band (4096 <= 4608).
    const int pbase = QA + wv * 4608;
    float rsum[8][4];
    {
        v8bf aq[8];   // hoisted: P stores below overwrite own Q rows
        #pragma unroll
        for (int uu = 0; uu < 8; ++uu) {
            const int h = uu >> 2, g = 4*wv + (uu & 3);
            aq[uu] = ldfrag(s16 + QA + (g*16 + lr)*72 + h*32 + lk*8);
        }
        #pragma unroll
        for (int uu = 0; uu < 8; ++uu) {
            const int h = uu >> 2, g = 4*wv + (uu & 3);
            v8bf bk = ldfrag(s16 + KA + (g*16 + lr)*72 + h*32 + lk*8);
            v4f zz = {0.f,0.f,0.f,0.f};
            v4f sc = MFMA(aq[uu], bk, zz);
            #pragma unroll
            for (int r = 0; r < 4; ++r) {
                const int row = lk*4 + r;
                const bool valid = ((lr >> 3) == (row >> 3)) && ((lr & 7) <= (row & 7));
                float e = valid ? __expf(sc[r]) : 0.f;
                float sum = e;
                sum += __shfl_xor(sum, 1);
                sum += __shfl_xor(sum, 2);
                sum += __shfl_xor(sum, 4);
                sum += __shfl_xor(sum, 8);
                rsum[uu][r] = frcp(sum);
                s16[pbase + uu*512 + row*32 + lr] = f2b(e);
            }
        }
    }

    // ---------- Ph2b: PV -> O (KA own band); V B-frag via __shfl from vpx/vpy ----------
    {
        const int s0 = lr + ((lk & 1) << 5);
        const int s1 = s0 + 16;
        #pragma unroll
        for (int uu = 0; uu < 8; ++uu) {
            const int mw = uu & 3, g = 4*wv + mw;
            v8bf ap = zfrag();
            if (lk < 2) ap = ldfrag(s16 + pbase + uu*512 + lr*32 + lk*8);
            #pragma unroll
            for (int dl = 0; dl < 2; ++dl) {
                const int dt = (uu >> 2)*2 + dl;
                v4u bw;
                bw[0] = __shfl(vpx[dt][mw], s0);
                bw[1] = __shfl(vpy[dt][mw], s0);
                bw[2] = __shfl(vpx[dt][mw], s1);
                bw[3] = __shfl(vpy[dt][mw], s1);
                if (lk >= 2) { bw[0] = 0; bw[1] = 0; bw[2] = 0; bw[3] = 0; }
                v8bf bv = __builtin_bit_cast(v8bf, bw);
                v4f zz = {0.f,0.f,0.f,0.f};
                v4f oc = MFMA(ap, bv, zz);
                #pragma unroll
                for (int r = 0; r < 4; ++r) {
                    const int row = g*16 + lk*4 + r;
                    s16[KA + row*72 + dt*16 + lr] = f2b(oc[r] * rsum[uu][r]);
                }
            }
        }
    }

    // ---------- Ph3: Wo GEMM + residual (emb re-gather) + norm2 -> x2n; pack x2 -> bf16 regs ----------
    unsigned x2p[4][4][2];   // residual x2 packed bf16 (frees 32 VGPRs across Ph4)
    {
        v8bf ao[4][2];
        #pragma unroll
        for (int mi = 0; mi < 4; ++mi)
            #pragma unroll
            for (int ks = 0; ks < 2; ++ks)
                ao[mi][ks] = ldfrag(s16 + KA + (wv*64 + mi*16 + lr)*72 + ks*32 + lk*8);
        v4f x2[4][4];
        #pragma unroll
        for (int mi = 0; mi < 4; ++mi) {
            int trow[4];
            #pragma unroll
            for (int r = 0; r < 4; ++r)
                trow[r] = tokens[p0*8 + wv*64 + mi*16 + lk*4 + r];
            #pragma unroll
            for (int nt = 0; nt < 4; ++nt)
                #pragma unroll
                for (int r = 0; r < 4; ++r)
                    x2[mi][nt][r] = emb[(size_t)trow[r] * 64 + nt*16 + lr];
        }
        #pragma unroll
        for (int nt = 0; nt < 4; ++nt) {
            v8bf b[2];
            #pragma unroll
            for (int ks = 0; ks < 2; ++ks)
                b[ks] = ldfrag(wt + 12288 + (nt*16 + lr)*64 + ks*32 + lk*8);
            #pragma unroll
            for (int mi = 0; mi < 4; ++mi)
                #pragma unroll
                for (int ks = 0; ks < 2; ++ks)
                    x2[mi][nt] = MFMA(ao[mi][ks], b[ks], x2[mi][nt]);
        }
        #pragma unroll
        for (int mi = 0; mi < 4; ++mi) {
            float ssq[4] = {0.f,0.f,0.f,0.f};
            #pragma unroll
            for (int nt = 0; nt < 4; ++nt)
                #pragma unroll
                for (int r = 0; r < 4; ++r) ssq[r] = fmaf(x2[mi][nt][r], x2[mi][nt][r], ssq[r]);
            #pragma unroll
            for (int r = 0; r < 4; ++r) {
                ssq[r] += __shfl_xor(ssq[r], 1);
                ssq[r] += __shfl_xor(ssq[r], 2);
                ssq[r] += __shfl_xor(ssq[r], 4);
                ssq[r] += __shfl_xor(ssq[r], 8);
                ssq[r] = frsq(ssq[r] * 0.015625f + EPS);
            }
            #pragma unroll
            for (int nt = 0; nt < 4; ++nt) {
                const float nv = n2w[nt*16 + lr];
                #pragma unroll
                for (int r = 0; r < 4; ++r) {
                    const int row = wv*64 + mi*16 + lk*4 + r;
                    s16[QA + row*72 + nt*16 + lr] = f2b(x2[mi][nt][r] * nv * ssq[r]);
                }
                x2p[mi][nt][0] = f2b2(x2[mi][nt][0], x2[mi][nt][1]);
                x2p[mi][nt][1] = f2b2(x2[mi][nt][2], x2[mi][nt][3]);
            }
        }
    }

    // ---------- Ph4: FFN1 + silu -> h [256][136] overlaying QA+KA ----------
    {
        v8bf a[4][2];
        #pragma unroll
        for (int mi = 0; mi < 4; ++mi)
            #pragma unroll
            for (int ks = 0; ks < 2; ++ks)
                a[mi][ks] = ldfrag(s16 + QA + (wv*64 + mi*16 + lr)*72 + ks*32 + lk*8);
        __syncthreads();   // BARRIER B: all pre-B reads done before h overwrites QA+KA
        #pragma unroll
        for (int nt = 0; nt < 8; ++nt) {
            v8bf b[2];
            #pragma unroll
            for (int ks = 0; ks < 2; ++ks)
                b[ks] = ldfrag(wt + 16384 + (nt*16 + lr)*64 + ks*32 + lk*8);
            #pragma unroll
            for (int mi = 0; mi < 4; ++mi) {
                v4f hc = {0.f,0.f,0.f,0.f};
                #pragma unroll
                for (int ks = 0; ks < 2; ++ks) hc = MFMA(a[mi][ks], b[ks], hc);
                #pragma unroll
                for (int r = 0; r < 4; ++r) {
                    const float v = hc[r];
                    const float sl = v * frcp(1.f + __expf(-v));
                    const int row = wv*64 + mi*16 + lk*4 + r;
                    s16[SHA + row*136 + nt*16 + lr] = f2b(sl);
                }
            }
        }
    }

    // ---------- Ph5: FFN2 (ks-outer, C-in = unpacked x2p) + norm3 + pool -> PO ----------
    {
        v4f acc[4][4];
        #pragma unroll
        for (int mi = 0; mi < 4; ++mi)
            #pragma unroll
            for (int nt = 0; nt < 4; ++nt) {
                acc[mi][nt][0] = b2f((u16)(x2p[mi][nt][0] & 0xffff));
                acc[mi][nt][1] = b2f((u16)(x2p[mi][nt][0] >> 16));
                acc[mi][nt][2] = b2f((u16)(x2p[mi][nt][1] & 0xffff));
                acc[mi][nt][3] = b2f((u16)(x2p[mi][nt][1] >> 16));
            }
        #pragma unroll
        for (int ks = 0; ks < 4; ++ks) {
            v8bf a2[4], bb[4];
            #pragma unroll
            for (int mi = 0; mi < 4; ++mi)
                a2[mi] = ldfrag(s16 + SHA + (wv*64 + mi*16 + lr)*136 + ks*32 + lk*8);
            #pragma unroll
            for (int nt = 0; nt < 4; ++nt)
                bb[nt] = ldfrag(wt + 24576 + (nt*16 + lr)*128 + ks*32 + lk*8);
            #pragma unroll
            for (int mi = 0; mi < 4; ++mi)
                #pragma unroll
                for (int nt = 0; nt < 4; ++nt)
                    acc[mi][nt] = MFMA(a2[mi], bb[nt], acc[mi][nt]);
        }
        #pragma unroll
        for (int mi = 0; mi < 4; ++mi) {
            float ssq[4] = {0.f,0.f,0.f,0.f};
            #pragma unroll
            for (int nt = 0; nt < 4; ++nt)
                #pragma unroll
                for (int r = 0; r < 4; ++r) ssq[r] = fmaf(acc[mi][nt][r], acc[mi][nt][r], ssq[r]);
            #pragma unroll
            for (int r = 0; r < 4; ++r) {
                ssq[r] += __shfl_xor(ssq[r], 1);
                ssq[r] += __shfl_xor(ssq[r], 2);
                ssq[r] += __shfl_xor(ssq[r], 4);
                ssq[r] += __shfl_xor(ssq[r], 8);
                ssq[r] = frsq(ssq[r] * 0.015625f + EPS);
            }
            const int lp = wv*8 + mi*2 + (lk >> 1);
            const int len = lengths[p0 + lp];
            const float invl = frcp((float)len);
            #pragma unroll
            for (int nt = 0; nt < 4; ++nt) {
                const float nv = nw[nt*16 + lr];
                float part = 0.f;
                #pragma unroll
                for (int r = 0; r < 4; ++r) {
                    const int tt = (lk & 1) * 4 + r;
                    const float xn3 = acc[mi][nt][r] * nv * ssq[r];
                    part += (tt < len) ? xn3 : 0.f;
                }
                part += __shfl_xor(part, 16);
                if ((lk & 1) == 0) {
                    const int addr = PO + lp*64
                        + (((2*nt + (lr >> 3)) ^ (lp & 7)) << 3) + (lr & 7);
                    s16[addr] = f2b(part * invl);
                }
            }
        }
    }
    __syncthreads();   // BARRIER C: pooled visible to all waves

    // ---------- Ph6: proj [32x64]@[64x128] + bias -> out ----------
    {
        #pragma unroll
        for (int mi = 0; mi < 2; ++mi) {
            v8bf ap2[2];
            #pragma unroll
            for (int ks = 0; ks < 2; ++ks)
                ap2[ks] = ldfrag(s16 + PO + (mi*16 + lr)*64 + (((ks*4 + lk) ^ (lr & 7)) << 3));
            #pragma unroll
            for (int ntl = 0; ntl < 2; ++ntl) {
                const int nt = wv*2 + ntl;
                v8bf b[2];
                #pragma unroll
                for (int ks = 0; ks < 2; ++ks)
                    b[ks] = ldfrag(wt + 32768 + (nt*16 + lr)*64 + ks*32 + lk*8);
                const float bias = pb[nt*16 + lr];
                v4f ac = {bias, bias, bias, bias};
                #pragma unroll
                for (int ks = 0; ks < 2; ++ks) ac = MFMA(ap2[ks], b[ks], ac);
                #pragma unroll
                for (int r = 0; r < 4; ++r)
                    out[(size_t)(p0 + mi*16 + lk*4 + r) * 128 + nt*16 + lr] = ac[r];
            }
        }
    }
}

extern "C" void kernel_launch(void* const* d_in, const int* in_sizes, int n_in,
                              void* d_out, int out_size, void* d_ws, size_t ws_size,
                              hipStream_t stream) {
    const int*   tokens  = (const int*)  d_in[0];
    const int*   lengths = (const int*)  d_in[1];
    const float* emb     = (const float*)d_in[2];
    const float* qkvw    = (const float*)d_in[3];
    const float* wo      = (const float*)d_in[4];
    const float* n1w     = (const float*)d_in[5];
    const float* n2w     = (const float*)d_in[6];
    const float* w1      = (const float*)d_in[7];
    const float* w2      = (const float*)d_in[8];
    const float* nw      = (const float*)d_in[9];
    const float* pw      = (const float*)d_in[10];
    const float* pb      = (const float*)d_in[11];
    float* outp = (float*)d_out;
    u16* wt = (u16*)d_ws;

    hipLaunchKernelGGL(prep_weights, dim3(160), dim3(256), 0, stream,
                       qkvw, wo, w1, w2, pw, wt);
    hipLaunchKernelGGL(enc_mfma, dim3(NP / 32), dim3(256), 0, stream,
                       tokens, lengths, emb, n1w, n2w, nw, pb, (const u16*)wt, outp);
}